// Round 1
// 197.270 us; speedup vs baseline: 1.0169x; 1.0169x over previous
//
#include <hip/hip_runtime.h>
#include <math.h>

#define B_ 4
#define S_ 2048
#define D_ 512
#define H_ 8
#define HD_ 64
#define SZ_ (B_ * S_ * D_)
#define WSZ_ (D_ * D_)   // 262144
#define BSH_ (B_ * S_ * H_)

// 0.125 * log2(e): folds the 1/sqrt(64) score scale and exp->exp2 into Qh.
#define QSCALE_ 0.18033688011112042f

typedef _Float16 v4h __attribute__((ext_vector_type(4)));
typedef _Float16 v8h __attribute__((ext_vector_type(8)));
typedef float    v4f __attribute__((ext_vector_type(4)));

// Async global->LDS, 16B per lane. LDS dest must be wave-uniform base
// (HW adds lane*16); global source is per-lane.
__device__ __forceinline__ void gload16(const void* g, void* l) {
    __builtin_amdgcn_global_load_lds((__attribute__((address_space(1))) void*)g,
                                     (__attribute__((address_space(3))) void*)l,
                                     16, 0, 0);
}

// ---------------------------------------------------------------------------
// R11: W[k][n] fp32 -> tile-ready swizzled f16 blocks.
// Layout: block(mat, nt, kc) = 16KB contiguous, 128 rows (n-local) x 64 k.
//   f16 index within block: r*64 + s*8 + j  holds  W[kc*64 + (s^(r&7))*8 + j][nt*128 + r]
// i.e. the st-16 XOR swizzle is baked in, so proj/outproj can stage it with
// linear global_load_lds and read ds_read_b128 with the same XOR (2-way, free).
// ---------------------------------------------------------------------------
__global__ __launch_bounds__(256) void wtrans_kernel(const float* __restrict__ Wq,
                                                     const float* __restrict__ Wo,
                                                     _Float16* __restrict__ Wt) {
    __shared__ float Ts[64][132];
    const int kc = blockIdx.x, nt = blockIdx.y, mat = blockIdx.z;
    const float* W = mat ? Wo : Wq;
    const int k0 = kc * 64, n0 = nt * 128;
    const int t = threadIdx.x;
#pragma unroll
    for (int i = 0; i < 8; i++) {
        int s2 = t + i * 256;
        int kk = s2 >> 5, nc = (s2 & 31) * 4;
        *(float4*)&Ts[kk][nc] = *(const float4*)&W[(size_t)(k0 + kk) * 512 + n0 + nc];
    }
    __syncthreads();
    _Float16* blk = Wt + (((size_t)mat * 4 + nt) * 8 + kc) * 8192;
#pragma unroll
    for (int i = 0; i < 4; i++) {
        int s2 = t + i * 256;
        int r = s2 >> 3, s = s2 & 7;
        int kl = (s ^ (r & 7)) * 8;
        v8h p;
#pragma unroll
        for (int j = 0; j < 8; j++) p[j] = (_Float16)Ts[kl + j][r];
        *(v8h*)&blk[r * 64 + s * 8] = p;
    }
}

// ---------------------------------------------------------------------------
// Projection with fused fp32->f16 cast. R11: B-tile staged by async
// global_load_lds from the pre-swizzled Wt blocks (no register round-trip,
// no B LDS writes); A stays reg-staged (needs the fp32->f16 cast).
// XCD-chunked block swizzle: the 4 n-tiles sharing an A panel land on the
// same XCD -> A re-reads hit that XCD's L2.
// z in {0,1,2} -> Qh (pre-scaled) / Kh / VT [B,H,HD,S(permuted)].
// ---------------------------------------------------------------------------
__global__ __launch_bounds__(256) void proj_mfma(const float* __restrict__ q,
                                                 const float* __restrict__ kin,
                                                 const float* __restrict__ v,
                                                 const _Float16* __restrict__ Wt,
                                                 const float* __restrict__ bq,
                                                 _Float16* __restrict__ Qh,
                                                 _Float16* __restrict__ Kh,
                                                 _Float16* __restrict__ VT) {
    __shared__ _Float16 As[128 * 72];
    __shared__ _Float16 Bs[128 * 64];
    // bijective XCD chunking: dispatch d executes logical block (d%8)*96 + d/8
    const int d   = blockIdx.x;
    const int wl  = (d & 7) * 96 + (d >> 3);
    const int z   = wl >> 8;            // 0..2
    const int rem = wl & 255;           // n fastest: 64 m-tiles x 4 n-tiles
    const int m0  = (rem >> 2) * 128;
    const int n_t = rem & 3, n0 = n_t * 128;
    const float* X = (z == 0) ? q : ((z == 1) ? kin : v);
    const int t    = threadIdx.x;
    const int lane = t & 63;
    const int w    = t >> 6;
    const int wm   = w >> 1, wn = w & 1;
    const int quad = lane >> 4, l16 = lane & 15;
    const _Float16* WtB = Wt + (size_t)n_t * 8 * 8192;   // mat 0 (Wq)

    v4f acc[4][4];
#pragma unroll
    for (int mi = 0; mi < 4; mi++)
#pragma unroll
        for (int ni = 0; ni < 4; ni++) acc[mi][ni] = (v4f)0.f;

    // A slots: 4/thread: slot s = t + i*256, row = s>>3, chunk = (s&7)*8
    int rr[4], cc[4];
    const float* Ap[4];
#pragma unroll
    for (int i = 0; i < 4; i++) {
        int s = t + i * 256;
        rr[i] = s >> 3;
        cc[i] = (s & 7) * 8;
        Ap[i] = X + (size_t)(m0 + rr[i]) * 512 + cc[i];
    }

    // Prologue: A tile 0 into VGPRs
    v4f pa[4][2];
#pragma unroll
    for (int i = 0; i < 4; i++) {
        pa[i][0] = *(const v4f*)(Ap[i] + 0);
        pa[i][1] = *(const v4f*)(Ap[i] + 4);
    }

    for (int k0 = 0; k0 < 512; k0 += 64) {
        v8h af4[4];
#pragma unroll
        for (int i = 0; i < 4; i++)
            af4[i] = __builtin_shufflevector(__builtin_convertvector(pa[i][0], v4h),
                                             __builtin_convertvector(pa[i][1], v4h),
                                             0, 1, 2, 3, 4, 5, 6, 7);
        __syncthreads();   // previous iteration's frag reads complete

        // async-stage B tile (16KB): wave w covers rows [w*32, w*32+32)
        {
            const _Float16* wsrc = WtB + (size_t)(k0 >> 6) * 8192 + w * 2048 + lane * 8;
            _Float16* ldst = &Bs[w * 2048];
#pragma unroll
            for (int i = 0; i < 4; i++) gload16(wsrc + i * 512, ldst + i * 512);
        }
#pragma unroll
        for (int i = 0; i < 4; i++)
            *(v8h*)&As[rr[i] * 72 + cc[i]] = af4[i];
        __syncthreads();   // drains vmcnt (Bs) + lgkmcnt (As)

        if (k0 + 64 < 512) {   // A prefetch overlaps the 32 MFMAs below
#pragma unroll
            for (int i = 0; i < 4; i++) {
                pa[i][0] = *(const v4f*)(Ap[i] + k0 + 64);
                pa[i][1] = *(const v4f*)(Ap[i] + k0 + 68);
            }
        }

#pragma unroll
        for (int ks = 0; ks < 2; ks++) {
            v8h af[4], bf[4];
#pragma unroll
            for (int mi = 0; mi < 4; mi++)
                af[mi] = *(const v8h*)&As[(wm * 64 + mi * 16 + l16) * 72 + ks * 32 + quad * 8];
#pragma unroll
            for (int ni = 0; ni < 4; ni++) {
                int row = wn * 64 + ni * 16 + l16;
                bf[ni] = *(const v8h*)&Bs[row * 64 + ((ks * 32 + quad * 8) ^ ((row & 7) * 8))];
            }
#pragma unroll
            for (int mi = 0; mi < 4; mi++)
#pragma unroll
                for (int ni = 0; ni < 4; ni++)
                    acc[mi][ni] = __builtin_amdgcn_mfma_f32_16x16x32_f16(af[mi], bf[ni], acc[mi][ni], 0, 0, 0);
        }
    }

    if (z < 2) {
        _Float16* Y = z ? Kh : Qh;
        const float sc = z ? 1.f : QSCALE_;
#pragma unroll
        for (int mi = 0; mi < 4; mi++) {
            int mb = m0 + wm * 64 + mi * 16 + quad * 4;
#pragma unroll
            for (int ni = 0; ni < 4; ni++) {
                int n = n0 + wn * 64 + ni * 16 + l16;
                float bj = bq[n];
#pragma unroll
                for (int r = 0; r < 4; r++)
                    Y[(size_t)(mb + r) * 512 + n] = (_Float16)((acc[mi][ni][r] + bj) * sc);
            }
        }
    } else {
#pragma unroll
        for (int mi = 0; mi < 4; mi++) {
            int tile0 = (m0 & 2047) + wm * 64;
            int pos = tile0 + (mi >> 1) * 32 + quad * 8 + (mi & 1) * 4;
            int b = m0 >> 11;
#pragma unroll
            for (int ni = 0; ni < 4; ni++) {
                int n = n0 + wn * 64 + ni * 16 + l16;
                int h = n >> 6, dd = n & 63;
                float bj = bq[n];
                v4h pk;
#pragma unroll
                for (int r = 0; r < 4; r++) pk[r] = (_Float16)(acc[mi][ni][r] + bj);
                *(v4h*)&VT[(((size_t)b * H_ + h) * HD_ + dd) * S_ + pos] = pk;
            }
        }
    }
}

// ---------------------------------------------------------------------------
// Output projection with fused split-K combine. R11: BK 32->64 (32 MFMAs per
// barrier drain, head index uniform per K-step), B via global_load_lds from
// pre-swizzled Wt (mat 1), XCD-chunked swizzle for Op L2 reuse.
// 64x128 tile, grid 512 (2 blocks/CU). Waves 2x2: wave = 32m x 64n.
// ---------------------------------------------------------------------------
__global__ __launch_bounds__(256) void outproj_mfma(const float* __restrict__ Op,
                                                    const float* __restrict__ lp,
                                                    const _Float16* __restrict__ Wt,
                                                    const float* __restrict__ bo,
                                                    float* __restrict__ out) {
    __shared__ _Float16 As[64 * 72];
    __shared__ _Float16 Bs[128 * 64];
    const int d   = blockIdx.x;
    const int wl  = (d & 7) * 64 + (d >> 3);
    const int n_t = wl & 3, n0 = n_t * 128;
    const int m0  = (wl >> 2) * 64;
    const int t    = threadIdx.x;
    const int lane = t & 63;
    const int w    = t >> 6;
    const int wm   = w >> 1, wn = w & 1;
    const int quad = lane >> 4, l16 = lane & 15;
    const _Float16* WtB = Wt + (size_t)(4 + n_t) * 8 * 8192;   // mat 1 (Wo)

    v4f acc[2][4];
#pragma unroll
    for (int mi = 0; mi < 2; mi++)
#pragma unroll
        for (int ni = 0; ni < 4; ni++) acc[mi][ni] = (v4f)0.f;

    // A slots: 2/thread: slot s = t + i*256, row = s>>3 (0..63), chunk=(s&7)*8
    int rw[2], cw[2];
    const float* O1p[2];
    const float* O2p[2];
    const float* lpp[2];
#pragma unroll
    for (int i = 0; i < 2; i++) {
        int s2 = t + i * 256;
        rw[i] = s2 >> 3;
        cw[i] = (s2 & 7) * 8;
        O1p[i] = Op + (size_t)(m0 + rw[i]) * 512 + cw[i];
        O2p[i] = O1p[i] + SZ_;
        lpp[i] = lp + (size_t)(m0 + rw[i]) * H_;
    }

    // Prologue: tile 0 (head 0; chunk offset < 64 so head is uniform per K-step)
    v4f pa0[2], pa1[2], pc0[2], pc1[2];
    float lvv[2];
#pragma unroll
    for (int i = 0; i < 2; i++) {
        pa0[i] = *(const v4f*)(O1p[i] + 0);
        pa1[i] = *(const v4f*)(O1p[i] + 4);
        pc0[i] = *(const v4f*)(O2p[i] + 0);
        pc1[i] = *(const v4f*)(O2p[i] + 4);
        lvv[i] = lpp[i][0] + lpp[i][BSH_];
    }

    for (int k0 = 0; k0 < 512; k0 += 64) {
        v8h af16[2];
#pragma unroll
        for (int i = 0; i < 2; i++) {
            float linv = __builtin_amdgcn_rcpf(lvv[i]);
            v4f sa = (pa0[i] + pc0[i]) * linv;
            v4f sb = (pa1[i] + pc1[i]) * linv;
            af16[i] = __builtin_shufflevector(__builtin_convertvector(sa, v4h),
                                              __builtin_convertvector(sb, v4h),
                                              0, 1, 2, 3, 4, 5, 6, 7);
        }
        __syncthreads();

        {
            const _Float16* wsrc = WtB + (size_t)(k0 >> 6) * 8192 + w * 2048 + lane * 8;
            _Float16* ldst = &Bs[w * 2048];
#pragma unroll
            for (int i = 0; i < 4; i++) gload16(wsrc + i * 512, ldst + i * 512);
        }
#pragma unroll
        for (int i = 0; i < 2; i++)
            *(v8h*)&As[rw[i] * 72 + cw[i]] = af16[i];
        __syncthreads();

        if (k0 + 64 < 512) {
            int kn = k0 + 64, hh = kn >> 6;
#pragma unroll
            for (int i = 0; i < 2; i++) {
                pa0[i] = *(const v4f*)(O1p[i] + kn);
                pa1[i] = *(const v4f*)(O1p[i] + kn + 4);
                pc0[i] = *(const v4f*)(O2p[i] + kn);
                pc1[i] = *(const v4f*)(O2p[i] + kn + 4);
                lvv[i] = lpp[i][hh] + lpp[i][BSH_ + hh];
            }
        }

#pragma unroll
        for (int ks = 0; ks < 2; ks++) {
            v8h af[2], bf[4];
#pragma unroll
            for (int mi = 0; mi < 2; mi++)
                af[mi] = *(const v8h*)&As[(wm * 32 + mi * 16 + l16) * 72 + ks * 32 + quad * 8];
#pragma unroll
            for (int ni = 0; ni < 4; ni++) {
                int row = wn * 64 + ni * 16 + l16;
                bf[ni] = *(const v8h*)&Bs[row * 64 + ((ks * 32 + quad * 8) ^ ((row & 7) * 8))];
            }
#pragma unroll
            for (int mi = 0; mi < 2; mi++)
#pragma unroll
                for (int ni = 0; ni < 4; ni++)
                    acc[mi][ni] = __builtin_amdgcn_mfma_f32_16x16x32_f16(af[mi], bf[ni], acc[mi][ni], 0, 0, 0);
        }
    }

#pragma unroll
    for (int mi = 0; mi < 2; mi++) {
        int mb = m0 + wm * 32 + mi * 16 + quad * 4;
#pragma unroll
        for (int ni = 0; ni < 4; ni++) {
            int n = n0 + wn * 64 + ni * 16 + l16;
            float bj = bo[n];
#pragma unroll
            for (int r = 0; r < 4; r++)
                out[(size_t)(mb + r) * 512 + n] = acc[mi][ni][r] + bj;
        }
    }
}

// ---------------------------------------------------------------------------
// Split-K MFMA f16 flash attention (FROZEN from R8: 57.9 µs verified).
// ---------------------------------------------------------------------------
__global__ __launch_bounds__(256) void flash_attn_f16(const _Float16* __restrict__ Qh,
                                                      const _Float16* __restrict__ Kh,
                                                      const _Float16* __restrict__ VT,
                                                      float* __restrict__ Op,
                                                      float* __restrict__ lp) {
    __shared__ _Float16 Ks[128 * 72];    // [key][d], pad 72
    __shared__ _Float16 Vs[64 * 136];    // [d][pos], pad 136

    const int t     = threadIdx.x;
    const int lane  = t & 63;
    const int w     = t >> 6;
    const int quad  = lane >> 4;
    const int l16   = lane & 15;
    const int q0    = blockIdx.x * 128;
    const int h     = blockIdx.y;
    const int b     = blockIdx.z >> 1;
    const int split = blockIdx.z & 1;

    const size_t base  = (size_t)b * S_ * D_ + (size_t)h * HD_;
    const size_t vbase = ((size_t)b * H_ + h) * HD_ * (size_t)S_;

    v8h qf[2][2];
#pragma unroll
    for (int nb = 0; nb < 2; nb++) {
        const _Float16* qrow = Qh + base + (size_t)(q0 + w * 32 + nb * 16 + l16) * D_;
        qf[nb][0] = *(const v8h*)(qrow + quad * 8);
        qf[nb][1] = *(const v8h*)(qrow + 32 + quad * 8);
    }

    v4f o[2][4];
#pragma unroll
    for (int nb = 0; nb < 2; nb++)
#pragma unroll
        for (int i = 0; i < 4; i++) o[nb][i] = (v4f)0.f;
    float l_lane[2] = {0.f, 0.f};

    const int kbeg = split * (S_ / 2);
    const int kend = kbeg + S_ / 2;

    v8h kv[4], vv[4];
#define LOADKV(kk)                                                             \
    do {                                                                       \
        _Pragma("unroll") for (int i = 0; i < 4; i++) {                        \
            int c = t + i * 256;                                               \
            kv[i] = *(const v8h*)(Kh + base + (size_t)((kk) + (c >> 3)) * D_ + (c & 7) * 8); \
            vv[i] = *(const v8h*)(VT + vbase + (size_t)(c >> 4) * S_ + (kk) + (c & 15) * 8); \
        }                                                                      \
    } while (0)

    LOADKV(kbeg);

    for (int kk0 = kbeg; kk0 < kend; kk0 += 128) {
        __syncthreads();
#pragma unroll
        for (int i = 0; i < 4; i++) {
            int c = t + i * 256;
            *(v8h*)&Ks[(c >> 3) * 72 + (c & 7) * 8] = kv[i];
            *(v8h*)&Vs[(c >> 4) * 136 + (c & 15) * 8] = vv[i];
        }
        __syncthreads();

        if (kk0 + 128 < kend) LOADKV(kk0 + 128);

#pragma unroll
        for (int hh = 0; hh < 2; hh++) {
            v4f sc[4][2];
#pragma unroll
            for (int mb = 0; mb < 4; mb++)
#pragma unroll
                for (int nb = 0; nb < 2; nb++) sc[mb][nb] = (v4f)0.f;
#pragma unroll
            for (int ks = 0; ks < 2; ks++) {
#pragma unroll
                for (int mb = 0; mb < 4; mb++) {
                    v8h ak = *(const v8h*)&Ks[(hh * 64 + mb * 16 + l16) * 72 + ks * 32 + quad * 8];
#pragma unroll
                    for (int nb = 0; nb < 2; nb++)
                        sc[mb][nb] = __builtin_amdgcn_mfma_f32_16x16x32_f16(ak, qf[nb][ks], sc[mb][nb], 0, 0, 0);
                }
            }

            v4h pf[4][2];
#pragma unroll
            for (int nb = 0; nb < 2; nb++) {
#pragma unroll
                for (int mb = 0; mb < 4; mb++) {
                    v4f pv;
#pragma unroll
                    for (int r = 0; r < 4; r++) pv[r] = __builtin_amdgcn_exp2f(sc[mb][nb][r]);
                    pf[mb][nb] = __builtin_convertvector(pv, v4h);
                    l_lane[nb] += (pv[0] + pv[1]) + (pv[2] + pv[3]);
                }
            }

#pragma unroll
            for (int p = 0; p < 2; p++) {
#pragma unroll
                for (int dblk = 0; dblk < 4; dblk++) {
                    v8h vf2 = *(const v8h*)&Vs[(dblk * 16 + l16) * 136 + hh * 64 + p * 32 + quad * 8];
                    v4h vlo = __builtin_shufflevector(vf2, vf2, 0, 1, 2, 3);
                    v4h vhi = __builtin_shufflevector(vf2, vf2, 4, 5, 6, 7);
#pragma unroll
                    for (int nb = 0; nb < 2; nb++) {
                        o[nb][dblk] = __builtin_amdgcn_mfma_f32_16x16x16f16(vlo, pf[2 * p][nb], o[nb][dblk], 0, 0, 0);
                        o[nb][dblk] = __builtin_amdgcn_mfma_f32_16x16x16f16(vhi, pf[2 * p + 1][nb], o[nb][dblk], 0, 0, 0);
                    }
                }
            }
        }
    }
#undef LOADKV

    float* Ops = Op + (size_t)split * SZ_;
#pragma unroll
    for (int nb = 0; nb < 2; nb++) {
        float rs = l_lane[nb];
        rs += __shfl_xor(rs, 16);
        rs += __shfl_xor(rs, 32);
        int qrow = q0 + w * 32 + nb * 16 + l16;
        if (quad == 0)
            lp[(size_t)split * BSH_ + ((size_t)b * S_ + qrow) * H_ + h] = rs;
        const size_t rbase = base + (size_t)qrow * D_;
#pragma unroll
        for (int dblk = 0; dblk < 4; dblk++)
            *(v4f*)&Ops[rbase + dblk * 16 + quad * 4] = o[nb][dblk];
    }
}

extern "C" void kernel_launch(void* const* d_in, const int* in_sizes, int n_in,
                              void* d_out, int out_size, void* d_ws, size_t ws_size,
                              hipStream_t stream) {
    const float* query = (const float*)d_in[0];
    const float* key   = (const float*)d_in[1];
    const float* value = (const float*)d_in[2];
    const float* Wq    = (const float*)d_in[3];
    const float* bq    = (const float*)d_in[4];
    const float* Wo    = (const float*)d_in[5];
    const float* bo    = (const float*)d_in[6];
    float* out = (float*)d_out;

    _Float16* ws = (_Float16*)d_ws;
    _Float16* Qh = ws;                                   // [B,S,D] f16
    _Float16* Kh = ws + (size_t)SZ_;                     // [B,S,D] f16
    _Float16* VT = ws + 2 * (size_t)SZ_;                 // [B,H,HD,S] f16 (permuted)
    _Float16* Wt = ws + 3 * (size_t)SZ_;                 // 2x[4 ntile][8 kchunk][128x64 swz] f16
    float*    Op = (float*)(ws + 3 * (size_t)SZ_ + 2 * (size_t)WSZ_);  // 2x[B,S,D] f32
    float*    lp = Op + 2 * (size_t)SZ_;                 // 2x[B,S,H] f32

    wtrans_kernel<<<dim3(8, 4, 2), 256, 0, stream>>>(Wq, Wo, Wt);
    proj_mfma<<<dim3(768), 256, 0, stream>>>(query, key, value, Wt, bq, Qh, Kh, VT);
    flash_attn_f16<<<dim3(S_ / 128, H_, B_ * 2), 256, 0, stream>>>(Qh, Kh, VT, Op, lp);
    outproj_mfma<<<dim3(512), 256, 0, stream>>>(Op, lp, Wt, bo, out);
}